// Round 5
// baseline (254.572 us; speedup 1.0000x reference)
//
#include <hip/hip_runtime.h>

#define NWT  62500          // 1,000,000 rows / 16 rows per wave-tile
#define GRID 1024
#define WPB  8              // waves per block (512 threads)
#define TOTW (GRID * WPB)   // 8192 waves total

typedef __attribute__((ext_vector_type(8))) short bf16x8;
typedef __attribute__((ext_vector_type(4))) float f32x4;

__device__ __forceinline__ short f2b(float f) {
    __bf16 h = (__bf16)f;                 // hardware RNE
    return __builtin_bit_cast(short, h);
}
__device__ __forceinline__ unsigned pack2(float lo, float hi) {
    return ((unsigned)(unsigned short)f2b(lo)) |
           (((unsigned)(unsigned short)f2b(hi)) << 16);
}
__device__ __forceinline__ float tanh_fast(float x) {
    float e = __expf(2.0f * x);
    return 1.0f - 2.0f * __builtin_amdgcn_rcpf(e + 1.0f);
}

// One gate: acc = Xaug @ Baug + S @ W   (12 x mfma_f32_16x16x32_bf16)
__device__ __forceinline__ void gate_mm(const char* lWg, const char* lBg,
                                        const int (&baOff)[4], const int (&wOff)[2][4],
                                        bf16x8 aX, bf16x8 aS0, bf16x8 aS1,
                                        f32x4 (&acc)[4])
{
    #pragma unroll
    for (int nt = 0; nt < 4; ++nt) {
        bf16x8 bx = *(const bf16x8*)(lBg + baOff[nt]);
        f32x4 z4 = {0.f, 0.f, 0.f, 0.f};
        acc[nt] = __builtin_amdgcn_mfma_f32_16x16x32_bf16(aX, bx, z4, 0, 0, 0);
    }
    #pragma unroll
    for (int ks = 0; ks < 2; ++ks) {
        bf16x8 a = ks ? aS1 : aS0;
        #pragma unroll
        for (int nt = 0; nt < 4; ++nt) {
            bf16x8 bw = *(const bf16x8*)(lWg + wOff[ks][nt]);
            acc[nt] = __builtin_amdgcn_mfma_f32_16x16x32_bf16(a, bw, acc[nt], 0, 0, 0);
        }
    }
}

__global__ __launch_bounds__(512, 4)
void dgm_lstm_kernel(const float* __restrict__ S, const float* __restrict__ X,
                     const float* __restrict__ U0, const float* __restrict__ U1,
                     const float* __restrict__ U2, const float* __restrict__ U3,
                     const float* __restrict__ W0, const float* __restrict__ W1,
                     const float* __restrict__ W2, const float* __restrict__ W3,
                     const float* __restrict__ b0, const float* __restrict__ b1,
                     const float* __restrict__ b2, const float* __restrict__ b3,
                     float* __restrict__ Out)
{
    // gate order: 0=z, 1=g, 2=r, 3=h
    __shared__ __align__(16) unsigned short lWT[4][64][64];   // 32 KB: W^T bf16, XOR-swizzled
    __shared__ __align__(16) unsigned short lBa[4][65][8];    // 4.1 KB: [U0,U1,U2,b,0..]; row 64 = zeros
    __shared__ __align__(16) unsigned short lR[WPB][2][16][64]; // 32 KB: (S*R), wave-private, double-buffered

    const int tid = threadIdx.x;

    // ---- one-time staging (u32-packed writes) ----
    {
        const float* Ws[4] = {W0, W1, W2, W3};
        #pragma unroll
        for (int g = 0; g < 4; ++g) {
            #pragma unroll
            for (int it = 0; it < 4; ++it) {
                int p  = it * 512 + tid;           // 0..2047
                int n  = p & 63;
                int k2 = (p >> 6) << 1;
                float w0 = Ws[g][k2 * 64 + n];
                float w1 = Ws[g][k2 * 64 + 64 + n];
                int byt = ((n << 7) + (k2 << 1)) ^ ((n & 7) << 4);
                *(unsigned*)((char*)(&lWT[0][0][0]) + (g << 13) + byt) = pack2(w0, w1);
            }
        }
        if (tid < 256) {
            const float* Us[4] = {U0, U1, U2, U3};
            const float* bs[4] = {b0, b1, b2, b3};
            int g = tid >> 6, n = tid & 63;
            bf16x8 f = {};
            f[0] = f2b(Us[g][n]);       f[1] = f2b(Us[g][64 + n]);
            f[2] = f2b(Us[g][128 + n]); f[3] = f2b(bs[g][n]);
            *(bf16x8*)(&lBa[g][n][0]) = f;
        } else if (tid < 260) {
            bf16x8 z = {};
            *(bf16x8*)(&lBa[tid - 256][64][0]) = z;
        }
    }
    __syncthreads();   // the only barrier; waves run independently below

    const int l   = tid & 63;
    const int wv  = tid >> 6;
    const int l15 = l & 15;
    const int lg  = l >> 4;

    char* lRb = (char*)(&lR[wv][0][0][0]);          // 4 KB per wave (2 x 2 KB buffers)
    const char* lWb = (const char*)(&lWT[0][0][0]);
    const char* lBb = (const char*)(&lBa[0][0][0]);

    // tile-invariant LDS byte offsets
    int baOff[4];
    #pragma unroll
    for (int nt = 0; nt < 4; ++nt)
        baOff[nt] = ((lg == 0) ? (l15 + (nt << 4)) : 64) << 4;
    int wOff[2][4];
    #pragma unroll
    for (int ks = 0; ks < 2; ++ks)
        #pragma unroll
        for (int nt = 0; nt < 4; ++nt) {
            int n = l15 + (nt << 4);
            wOff[ks][nt] = ((n << 7) + (ks << 6) + (lg << 4)) ^ ((n & 7) << 4);
        }
    int rdOff[2];
    #pragma unroll
    for (int ks = 0; ks < 2; ++ks)
        rdOff[ks] = ((l15 << 7) + (ks << 6) + (lg << 4)) ^ ((l15 & 7) << 4);

    const int gw = blockIdx.x * WPB + wv;   // global wave id (< NWT always)
    const short one_bf = (short)0x3F80;

    // ---- pipeline state ----
    float4 nsa0, nsa1, nsa2, nsa3;          // prefetched S A-fragment data (f32)
    float  nx0 = 0.f, nx1 = 0.f, nx2 = 0.f; // prefetched X
    float  zs[4][4], gq[4][4];              // carried H-state of previous tile
    bf16x8 aXp = {};
    int    prevRow0 = 0;
    int    par = 0;

    auto PREFETCH = [&](int t) {
        if (t < NWT) {
            int r0 = t << 4;
            const float* Sr = S + (size_t)(r0 + l15) * 64 + (lg << 3);
            nsa0 = *(const float4*)(Sr);      nsa1 = *(const float4*)(Sr + 4);
            nsa2 = *(const float4*)(Sr + 32); nsa3 = *(const float4*)(Sr + 36);
            if (lg == 0) {
                const float* Xr = X + (size_t)(r0 + l15) * 3;
                nx0 = Xr[0]; nx1 = Xr[1]; nx2 = Xr[2];
            }
        }
    };

    // R,Z,G phases for tile wt; leaves zs/gq/aXp/prevRow0 set, lR[par] written, par flipped
    auto RZG = [&](int wt) {
        const int row0 = wt << 4;

        // build fragments from prefetched data (vmcnt wait lands at first use)
        bf16x8 aS0, aS1, aX = {};
        aS0[0] = f2b(nsa0.x); aS0[1] = f2b(nsa0.y); aS0[2] = f2b(nsa0.z); aS0[3] = f2b(nsa0.w);
        aS0[4] = f2b(nsa1.x); aS0[5] = f2b(nsa1.y); aS0[6] = f2b(nsa1.z); aS0[7] = f2b(nsa1.w);
        aS1[0] = f2b(nsa2.x); aS1[1] = f2b(nsa2.y); aS1[2] = f2b(nsa2.z); aS1[3] = f2b(nsa2.w);
        aS1[4] = f2b(nsa3.x); aS1[5] = f2b(nsa3.y); aS1[6] = f2b(nsa3.z); aS1[7] = f2b(nsa3.w);
        aX[0] = f2b(nx0); aX[1] = f2b(nx1); aX[2] = f2b(nx2);
        aX[3] = (lg == 0) ? one_bf : (short)0;

        // issue next tile's loads (hidden under this tile's compute)
        PREFETCH(wt + TOTW);

        // C-layout S loads (L1/L2 hot; consumed ~400cy later at R epilogue)
        float sv[4][4];
        const float* Sc = S + (size_t)(row0 + (lg << 2)) * 64 + l15;
        #pragma unroll
        for (int m = 0; m < 4; ++m)
            #pragma unroll
            for (int nt = 0; nt < 4; ++nt)
                sv[m][nt] = Sc[m * 64 + (nt << 4)];

        f32x4 acc[4];
        char* lRw = lRb + (par << 11);

        // gate R: write s*r into wave-private lR[par]
        gate_mm(lWb + (2 << 13), lBb + 2 * 1040, baOff, wOff, aX, aS0, aS1, acc);
        #pragma unroll
        for (int nt = 0; nt < 4; ++nt) {
            #pragma unroll
            for (int m = 0; m < 4; ++m) {
                float t  = tanh_fast(acc[nt][m]);
                float sr = sv[m][nt] * t;
                int rowm = (lg << 2) + m;
                int byt  = ((rowm << 7) + ((l15 + (nt << 4)) << 1)) ^ ((rowm & 7) << 4);
                *(unsigned short*)(lRw + byt) = (unsigned short)f2b(sr);
            }
        }

        // gate Z (fuse zs = z*sv; sv dies here)
        gate_mm(lWb, lBb, baOff, wOff, aX, aS0, aS1, acc);
        #pragma unroll
        for (int nt = 0; nt < 4; ++nt)
            #pragma unroll
            for (int m = 0; m < 4; ++m)
                zs[nt][m] = tanh_fast(acc[nt][m]) * sv[m][nt];

        // gate G
        gate_mm(lWb + (1 << 13), lBb + 1040, baOff, wOff, aX, aS0, aS1, acc);
        #pragma unroll
        for (int nt = 0; nt < 4; ++nt)
            #pragma unroll
            for (int m = 0; m < 4; ++m)
                gq[nt][m] = 1.0f - tanh_fast(acc[nt][m]);

        aXp = aX; prevRow0 = row0; par ^= 1;
    };

    // deferred H + combine + store for the tile staged one iteration ago
    auto HCOMB = [&]() {
        const char* lRp = lRb + ((par ^ 1) << 11);
        bf16x8 aR0 = *(const bf16x8*)(lRp + rdOff[0]);
        bf16x8 aR1 = *(const bf16x8*)(lRp + rdOff[1]);
        f32x4 acc[4];
        gate_mm(lWb + (3 << 13), lBb + 3 * 1040, baOff, wOff, aXp, aR0, aR1, acc);
        float* Or = Out + (size_t)(prevRow0 + (lg << 2)) * 64 + l15;
        #pragma unroll
        for (int nt = 0; nt < 4; ++nt) {
            #pragma unroll
            for (int m = 0; m < 4; ++m) {
                float h = tanh_fast(acc[nt][m]);
                Or[m * 64 + (nt << 4)] = fmaf(gq[nt][m], h, zs[nt][m]);
            }
        }
    };

    // ---- pipelined main loop (no fences, no barriers) ----
    PREFETCH(gw);
    RZG(gw);
    for (int wt = gw + TOTW; wt < NWT; wt += TOTW) {
        HCOMB();        // tile t-1: lR writes are >600cy old; runs under vmcnt wait
        RZG(wt);        // tile t
    }
    HCOMB();            // drain
}

extern "C" void kernel_launch(void* const* d_in, const int* in_sizes, int n_in,
                              void* d_out, int out_size, void* d_ws, size_t ws_size,
                              hipStream_t stream) {
    dim3 grid(GRID), block(512);
    dgm_lstm_kernel<<<grid, block, 0, stream>>>(
        (const float*)d_in[0],  (const float*)d_in[1],
        (const float*)d_in[2],  (const float*)d_in[3],
        (const float*)d_in[4],  (const float*)d_in[5],
        (const float*)d_in[6],  (const float*)d_in[7],
        (const float*)d_in[8],  (const float*)d_in[9],
        (const float*)d_in[10], (const float*)d_in[11],
        (const float*)d_in[12], (const float*)d_in[13],
        (float*)d_out);
}

// Round 6
// 132.814 us; speedup vs baseline: 1.9168x; 1.9168x over previous
//
#include <hip/hip_runtime.h>

#define NWT   62500          // 1,000,000 rows / 16 rows per wave-tile
#define GRID  512
#define WPB   4              // waves per block (256 threads)
#define TOTW  (GRID * WPB)   // 2048 waves

typedef __attribute__((ext_vector_type(8))) short bf16x8;
typedef __attribute__((ext_vector_type(4))) float f32x4;

static __device__ __forceinline__ short f2b(float f) {
    __bf16 h = (__bf16)f;                 // hardware RNE
    return __builtin_bit_cast(short, h);
}
static __device__ __forceinline__ float b2f(short s) {
    unsigned u = ((unsigned)(unsigned short)s) << 16;
    return __builtin_bit_cast(float, u);
}
static __device__ __forceinline__ unsigned pack2(float lo, float hi) {
    return ((unsigned)(unsigned short)f2b(lo)) |
           (((unsigned)(unsigned short)f2b(hi)) << 16);
}
static __device__ __forceinline__ float tanh_fast(float x) {
    float e = __expf(2.0f * x);
    return 1.0f - 2.0f * __builtin_amdgcn_rcpf(e + 1.0f);
}

// acc = Xaug @ Baug(LDS) + A @ W(registers)   (12 x mfma_f32_16x16x32_bf16)
static __device__ __forceinline__ void gate_mm(const bf16x8 (&wR)[2][4],
                                               const char* lBg, const int (&baOff)[4],
                                               bf16x8 aX, bf16x8 a0, bf16x8 a1,
                                               f32x4 (&acc)[4])
{
    #pragma unroll
    for (int nt = 0; nt < 4; ++nt) {
        bf16x8 bx = *(const bf16x8*)(lBg + baOff[nt]);
        f32x4 z4 = {0.f, 0.f, 0.f, 0.f};
        acc[nt] = __builtin_amdgcn_mfma_f32_16x16x32_bf16(aX, bx, z4, 0, 0, 0);
    }
    #pragma unroll
    for (int ks = 0; ks < 2; ++ks) {
        bf16x8 a = ks ? a1 : a0;
        #pragma unroll
        for (int nt = 0; nt < 4; ++nt)
            acc[nt] = __builtin_amdgcn_mfma_f32_16x16x32_bf16(a, wR[ks][nt], acc[nt], 0, 0, 0);
    }
}

__global__ __launch_bounds__(256, 2)
void dgm_lstm_kernel(const float* __restrict__ S, const float* __restrict__ X,
                     const float* __restrict__ U0, const float* __restrict__ U1,
                     const float* __restrict__ U2, const float* __restrict__ U3,
                     const float* __restrict__ W0, const float* __restrict__ W1,
                     const float* __restrict__ W2, const float* __restrict__ W3,
                     const float* __restrict__ b0, const float* __restrict__ b1,
                     const float* __restrict__ b2, const float* __restrict__ b3,
                     float* __restrict__ Out)
{
    // gate order: 0=z, 1=g, 2=r, 3=h
    __shared__ __align__(16) unsigned short lWT[4][64][64]; // 32 KB: W^T bf16 (staging only)
    __shared__ __align__(16) unsigned short lBa[4][65][8];  // 4.1 KB: [U0,U1,U2,b,0..]; row 64 = zeros
    __shared__ __align__(16) float          lS[WPB][16][68];// 17 KB: S tile f32, wave-private, pad->68
    __shared__ __align__(16) unsigned short lR[WPB][16][64];// 8 KB: R bf16, wave-private

    const int tid = threadIdx.x;

    // ---- one-time staging: W^T bf16 swizzled; Baug table ----
    {
        const float* Ws[4] = {W0, W1, W2, W3};
        #pragma unroll
        for (int g = 0; g < 4; ++g) {
            #pragma unroll
            for (int it = 0; it < 8; ++it) {
                int p  = it * 256 + tid;            // 0..2047
                int n  = p & 63;
                int k2 = (p >> 6) << 1;
                float w0 = Ws[g][k2 * 64 + n];
                float w1 = Ws[g][k2 * 64 + 64 + n];
                int byt = ((n << 7) + (k2 << 1)) ^ ((n & 7) << 4);
                *(unsigned*)((char*)(&lWT[0][0][0]) + (g << 13) + byt) = pack2(w0, w1);
            }
        }
        const float* Us[4] = {U0, U1, U2, U3};
        const float* bs[4] = {b0, b1, b2, b3};
        int g = tid >> 6, n = tid & 63;
        bf16x8 f = {};
        f[0] = f2b(Us[g][n]);       f[1] = f2b(Us[g][64 + n]);
        f[2] = f2b(Us[g][128 + n]); f[3] = f2b(bs[g][n]);
        *(bf16x8*)(&lBa[g][n][0]) = f;
        if (tid < 4) { bf16x8 z = {}; *(bf16x8*)(&lBa[tid][64][0]) = z; }
    }
    __syncthreads();

    const int l   = tid & 63;
    const int wv  = tid >> 6;
    const int l15 = l & 15;
    const int lg  = l >> 4;

    const char* lWb = (const char*)(&lWT[0][0][0]);
    const char* lBb = (const char*)(&lBa[0][0][0]);
    char*       lRw = (char*)(&lR[wv][0][0]);

    // ---- load ALL weight B-fragments into registers (loop-invariant, 128 VGPR) ----
    bf16x8 wReg[4][2][4];
    {
        #pragma unroll
        for (int g = 0; g < 4; ++g)
            #pragma unroll
            for (int ks = 0; ks < 2; ++ks)
                #pragma unroll
                for (int nt = 0; nt < 4; ++nt) {
                    int n = l15 + (nt << 4);
                    int byt = ((n << 7) + (ks << 6) + (lg << 4)) ^ ((n & 7) << 4);
                    wReg[g][ks][nt] = *(const bf16x8*)(lWb + (g << 13) + byt);
                }
    }

    // tile-invariant offsets
    int baOff[4];
    #pragma unroll
    for (int nt = 0; nt < 4; ++nt)
        baOff[nt] = ((lg == 0) ? (l15 + (nt << 4)) : 64) << 4;
    int rdOff[2];
    #pragma unroll
    for (int ks = 0; ks < 2; ++ks)
        rdOff[ks] = ((l15 << 7) + (ks << 6) + (lg << 4)) ^ ((l15 & 7) << 4);

    const int gw = blockIdx.x * WPB + wv;   // global wave id (< TOTW <= NWT)
    const short one_bf = (short)0x3F80;

    // ---- prologue prefetch (depth 1) ----
    float4 p0, p1, p2, p3;
    float  px0 = 0.f, px1 = 0.f, px2 = 0.f;
    {
        const float* Sr = S + (size_t)((gw << 4) + l15) * 64 + (lg << 3);
        p0 = *(const float4*)(Sr);      p1 = *(const float4*)(Sr + 4);
        p2 = *(const float4*)(Sr + 32); p3 = *(const float4*)(Sr + 36);
        if (lg == 0) {
            const float* Xr = X + (size_t)((gw << 4) + l15) * 3;
            px0 = Xr[0]; px1 = Xr[1]; px2 = Xr[2];
        }
    }

    for (int wt = gw; wt < NWT; wt += TOTW) {
        const int row0 = wt << 4;

        // ---- 1. stage S tile to wave-private LDS (f32, A-layout rows, stride 68) ----
        float* lSr = &lS[wv][l15][0];
        *(float4*)(lSr + (lg << 3))      = p0;
        *(float4*)(lSr + (lg << 3) + 4)  = p1;
        *(float4*)(lSr + (lg << 3) + 32) = p2;
        *(float4*)(lSr + (lg << 3) + 36) = p3;

        // ---- 2. build bf16 fragments from the same registers ----
        bf16x8 aS0, aS1, aX = {};
        aS0[0] = f2b(p0.x); aS0[1] = f2b(p0.y); aS0[2] = f2b(p0.z); aS0[3] = f2b(p0.w);
        aS0[4] = f2b(p1.x); aS0[5] = f2b(p1.y); aS0[6] = f2b(p1.z); aS0[7] = f2b(p1.w);
        aS1[0] = f2b(p2.x); aS1[1] = f2b(p2.y); aS1[2] = f2b(p2.z); aS1[3] = f2b(p2.w);
        aS1[4] = f2b(p3.x); aS1[5] = f2b(p3.y); aS1[6] = f2b(p3.z); aS1[7] = f2b(p3.w);
        aX[0] = f2b(px0); aX[1] = f2b(px1); aX[2] = f2b(px2);
        aX[3] = (lg == 0) ? one_bf : (short)0;

        // ---- 3. issue next tile's loads (registers now free; latency hides under gates) ----
        int tn = wt + TOTW;
        if (tn < NWT) {
            const float* Sr = S + (size_t)((tn << 4) + l15) * 64 + (lg << 3);
            p0 = *(const float4*)(Sr);      p1 = *(const float4*)(Sr + 4);
            p2 = *(const float4*)(Sr + 32); p3 = *(const float4*)(Sr + 36);
            if (lg == 0) {
                const float* Xr = X + (size_t)((tn << 4) + l15) * 3;
                px0 = Xr[0]; px1 = Xr[1]; px2 = Xr[2];
            }
        }

        // ---- 4. fence lS writes, then issue C-layout sv reads (consumed at Z-epi) ----
        asm volatile("s_waitcnt lgkmcnt(0)" ::: "memory");
        float sv[4][4];
        #pragma unroll
        for (int m = 0; m < 4; ++m)
            #pragma unroll
            for (int nt = 0; nt < 4; ++nt)
                sv[m][nt] = lS[wv][(lg << 2) + m][l15 + (nt << 4)];

        f32x4 acc[4];

        // ---- gate R: write r (bf16, C-layout swizzled) into wave-private lR ----
        gate_mm(wReg[2], lBb + 2 * 1040, baOff, aX, aS0, aS1, acc);
        #pragma unroll
        for (int nt = 0; nt < 4; ++nt) {
            int n = l15 + (nt << 4);
            #pragma unroll
            for (int m = 0; m < 4; ++m) {
                float t  = tanh_fast(acc[nt][m]);
                int rowm = (lg << 2) + m;
                int byt  = ((rowm << 7) + (n << 1)) ^ ((rowm & 7) << 4);
                *(unsigned short*)(lRw + byt) = (unsigned short)f2b(t);
            }
        }

        // ---- gate Z: zs = tanh * sv (sv dies) ----
        float zs[4][4];
        gate_mm(wReg[0], lBb, baOff, aX, aS0, aS1, acc);
        #pragma unroll
        for (int nt = 0; nt < 4; ++nt)
            #pragma unroll
            for (int m = 0; m < 4; ++m)
                zs[nt][m] = tanh_fast(acc[nt][m]) * sv[m][nt];

        // ---- gate G ----
        float gq[4][4];
        gate_mm(wReg[1], lBb + 1040, baOff, aX, aS0, aS1, acc);
        #pragma unroll
        for (int nt = 0; nt < 4; ++nt)
            #pragma unroll
            for (int m = 0; m < 4; ++m)
                gq[nt][m] = 1.0f - tanh_fast(acc[nt][m]);

        // ---- gate H: read r back in A-layout, S*R from registers ----
        asm volatile("s_waitcnt lgkmcnt(0)" ::: "memory");
        bf16x8 aR0 = *(const bf16x8*)(lRw + rdOff[0]);
        bf16x8 aR1 = *(const bf16x8*)(lRw + rdOff[1]);
        bf16x8 aH0, aH1;
        #pragma unroll
        for (int i = 0; i < 8; ++i) {
            aH0[i] = f2b(b2f(aS0[i]) * b2f(aR0[i]));
            aH1[i] = f2b(b2f(aS1[i]) * b2f(aR1[i]));
        }
        gate_mm(wReg[3], lBb + 3 * 1040, baOff, aX, aH0, aH1, acc);

        // ---- epilogue: combine + store ----
        float* Or = Out + (size_t)(row0 + (lg << 2)) * 64 + l15;
        #pragma unroll
        for (int nt = 0; nt < 4; ++nt) {
            #pragma unroll
            for (int m = 0; m < 4; ++m) {
                float h = tanh_fast(acc[nt][m]);
                Or[m * 64 + (nt << 4)] = fmaf(gq[nt][m], h, zs[nt][m]);
            }
        }
    }
}

extern "C" void kernel_launch(void* const* d_in, const int* in_sizes, int n_in,
                              void* d_out, int out_size, void* d_ws, size_t ws_size,
                              hipStream_t stream) {
    dim3 grid(GRID), block(256);
    dgm_lstm_kernel<<<grid, block, 0, stream>>>(
        (const float*)d_in[0],  (const float*)d_in[1],
        (const float*)d_in[2],  (const float*)d_in[3],
        (const float*)d_in[4],  (const float*)d_in[5],
        (const float*)d_in[6],  (const float*)d_in[7],
        (const float*)d_in[8],  (const float*)d_in[9],
        (const float*)d_in[10], (const float*)d_in[11],
        (const float*)d_in[12], (const float*)d_in[13],
        (float*)d_out);
}